// Round 17
// baseline (12079.941 us; speedup 1.0000x reference)
//
#include <hip/hip_runtime.h>
#include <hip/hip_bf16.h>

#define B_ 32
#define T_ 2048
#define D_ 512
#define H_ 1024
#define NBLK 128   // 2 batch-groups x 64 col-groups; 1 block/CU, co-resident
#define CG_ 64     // col groups
#define JPB 16     // h-columns per col-group (H_/CG_)
#define MROW 16    // batch rows per batch-group

typedef __attribute__((ext_vector_type(8))) short short8;
typedef __attribute__((ext_vector_type(4))) float f32x4;
typedef __attribute__((ext_vector_type(4))) int i32x4;

__device__ __forceinline__ float sigmoidf_(float x) { return 1.0f / (1.0f + __expf(-x)); }
__device__ __forceinline__ float tanhf_(float x) {
  float e = __expf(2.0f * x);
  return 1.0f - 2.0f / (e + 1.0f);
}
__device__ __forceinline__ unsigned short f_to_bf16bits(float f) {
  __hip_bfloat16 h = __float2bfloat16(f);
  return __builtin_bit_cast(unsigned short, h);
}

// 16B load bypassing L1/L2 (sc0 sc1): issue-only; explicit vmcnt follows.
__device__ __forceinline__ i32x4 load16_sys(const void* p) {
  i32x4 v;
  asm volatile("global_load_dwordx4 %0, %1, off sc0 sc1" : "=v"(v) : "v"(p));
  return v;
}
// 4B LLC-fresh load, value ready on return (poll-loop fallback).
__device__ __forceinline__ int load4_sys(const int* p) {
  int v;
  asm volatile("global_load_dword %0, %1, off sc0 sc1\n\t"
               "s_waitcnt vmcnt(0)"
               : "=v"(v) : "v"(p) : "memory");
  return v;
}
// Fire-and-forget 4B sample. EARLY-CLOBBER dest: the address (loop-invariant,
// held live across iterations) must never be allocated under the in-flight
// load's destination (R16 crash root cause).
__device__ __forceinline__ void issue4_sys(const int* p, int& v) {
  asm volatile("global_load_dword %0, %1, off sc0 sc1" : "=&v"(v) : "v"(p));
}
// 16B store written through to LLC (sc0 sc1); drained by explicit vmcnt(0).
__device__ __forceinline__ void store16_sys(void* p, i32x4 v) {
  asm volatile("global_store_dwordx4 %0, %1, off sc0 sc1" :: "v"(p), "v"(v) : "memory");
}

// ---------------------------------------------------------------------------
// FUSED persistent LSTM = R15 verified structure (single barrier + LDS
// counter + block flag) + FLAG-SAMPLE PREFETCH:
//  - At the end of step t (after our flag post) each wave fire-and-forgets a
//    sample of its 16 producer flags. At the top of step t+1, after the
//    x-part (compiler waits drain the sample; explicit vmcnt(0) guarantees
//    it), the sample is checked: all >= t+1 -> skip the poll (one LLC RT off
//    the critical path). Miss -> R15's verified poll loop. Flags monotone =>
//    a stale sample only under-reports; protocol untouched (read-only).
// Safety induction on hbuf/flags identical to R12/R14/R15 (verified).
// ---------------------------------------------------------------------------
__global__ __launch_bounds__(256, 1) void lstm_rec(
    const float* __restrict__ x, const float* __restrict__ Wih,
    const float* __restrict__ Whh,
    const int* __restrict__ lengths, const float* __restrict__ h0,
    const float* __restrict__ c0, const float* __restrict__ bih,
    const float* __restrict__ bhh, __hip_bfloat16* hbuf,
    int* flags, float* __restrict__ out) {
  __shared__ float Gs[2][4][MROW][68];   // [parity][k-slice][batch row][gate col]
  __shared__ int cnt[2];                 // per-parity completion counters

  const int bid = blockIdx.x, tid = threadIdx.x;
  const int bg = bid & 1, cg = bid >> 1;
  const int lane = tid & 63, w = tid >> 6;
  const int lr = lane & 15, q = lane >> 4, kq = q * 8;
  const int kkb = w * 8;                 // h-part kk range [kkb,kkb+8)

  // --- W_hh fragments (stationary) ---
  short8 wf[4][8];
#pragma unroll
  for (int ni = 0; ni < 4; ++ni) {
    const int gcol = ni * H_ + cg * JPB + lr;
    const float* wbase = Whh + (size_t)gcol * H_ + kq;
#pragma unroll
    for (int kk2 = 0; kk2 < 8; ++kk2) {
      const int k0 = (kkb + kk2) * 32;
      f32x4 w0 = *(const f32x4*)(wbase + k0);
      f32x4 w1 = *(const f32x4*)(wbase + k0 + 4);
      __hip_bfloat16 tw_[8];
#pragma unroll
      for (int e = 0; e < 4; ++e) { tw_[e] = __float2bfloat16(w0[e]); tw_[4 + e] = __float2bfloat16(w1[e]); }
      wf[ni][kk2] = *(const short8*)&tw_[0];
    }
  }
  // --- W_ih fragments (stationary): x-part K-slice [w*128,+128) of D ---
  short8 wfx[4][4];
#pragma unroll
  for (int ni = 0; ni < 4; ++ni) {
    const int gcol = ni * H_ + cg * JPB + lr;
    const float* wbase = Wih + (size_t)gcol * D_ + w * 128 + kq;
#pragma unroll
    for (int kkx = 0; kkx < 4; ++kkx) {
      f32x4 w0 = *(const f32x4*)(wbase + kkx * 32);
      f32x4 w1 = *(const f32x4*)(wbase + kkx * 32 + 4);
      __hip_bfloat16 tw_[8];
#pragma unroll
      for (int e = 0; e < 4; ++e) { tw_[e] = __float2bfloat16(w0[e]); tw_[4 + e] = __float2bfloat16(w1[e]); }
      wfx[ni][kkx] = *(const short8*)&tw_[0];
    }
  }

  if (tid < 2) cnt[tid] = 0;   // visible to all by the step-0 barrier

  const int bloc = tid >> 4, j1 = tid & 15;
  const int b = bg * MROW + bloc;
  const int jglob = cg * JPB + j1;
  const int len_b = lengths[b];
  int maxlen = 0;
  for (int p = 0; p < B_; ++p) maxlen = max(maxlen, lengths[p]);
  const int tend = maxlen;

  float hreg = h0[b * H_ + jglob], creg = c0[b * H_ + jglob];
  float bias[4];
#pragma unroll
  for (int p = 0; p < 4; ++p) bias[p] = bih[p * H_ + jglob] + bhh[p * H_ + jglob];

  const int* myflag = &flags[bg * CG_ + w * 16 + lr];
  char* const hstore_base = (char*)hbuf;
  const size_t poff = (size_t)b * (H_ * 2) + cg * (JPB * 2) + ((tid >> 3) & 1) * 16;
  const float* xrow = x + (size_t)(bg * MROW + lr) * T_ * D_ + w * 128 + kq;

  // preloop flag sample for t=0 (flags zeroed by init_k -> guaranteed hit)
  int fsamp;
  issue4_sys(myflag, fsamp);

  for (int t = 0; t < tend; ++t) {
    // ---- x-part: load x (cacheable, L2/L3), convert, 16 MFMAs ----
    // Independent of h -> fills the flag-wait bubble.
    f32x4 acc[4];
#pragma unroll
    for (int ni = 0; ni < 4; ++ni) acc[ni] = (f32x4){0.f, 0.f, 0.f, 0.f};
    {
      const float* xt = xrow + (size_t)t * D_;
      short8 afx[4];
#pragma unroll
      for (int kkx = 0; kkx < 4; ++kkx) {
        f32x4 a0 = *(const f32x4*)(xt + kkx * 32);
        f32x4 a1 = *(const f32x4*)(xt + kkx * 32 + 4);
        __hip_bfloat16 ta_[8];
#pragma unroll
        for (int e = 0; e < 4; ++e) { ta_[e] = __float2bfloat16(a0[e]); ta_[4 + e] = __float2bfloat16(a1[e]); }
        afx[kkx] = *(const short8*)&ta_[0];
      }
#pragma unroll
      for (int kkx = 0; kkx < 4; ++kkx)
#pragma unroll
        for (int ni = 0; ni < 4; ++ni)
          acc[ni] = __builtin_amdgcn_mfma_f32_16x16x32_bf16(afx[kkx], wfx[ni][kkx], acc[ni], 0, 0, 0);
    }

    // ---- flag check: prefetched sample first, poll loop only on miss ----
    asm volatile("s_waitcnt vmcnt(0)" ::: "memory");   // sample surely landed
    __builtin_amdgcn_sched_barrier(0);
    if (!__all((lane >= 16) || (fsamp >= t))) {
      while (true) {
        int f = load4_sys(myflag);
        if (__all((lane >= 16) || (f >= t))) break;
        __builtin_amdgcn_s_sleep(1);
      }
    }

    // ---- A-fragments: coalescing 16B L2-bypass loads (16 rows only) ----
    const char* hb = (const char*)(hbuf + (size_t)(t & 1) * (B_ * H_));
    const char* rowp = hb + (size_t)(bg * MROW + lr) * (H_ * 2) + kkb * 64 + q * 16;
    i32x4 raw[8];
#pragma unroll
    for (int kk2 = 0; kk2 < 8; ++kk2)
      raw[kk2] = load16_sys(rowp + kk2 * 64);
    asm volatile("s_waitcnt vmcnt(0)" ::: "memory");
    __builtin_amdgcn_sched_barrier(0);

    short8 af[8];
#pragma unroll
    for (int kk2 = 0; kk2 < 8; ++kk2) {
      union { i32x4 i; short8 s; } cv;
      cv.i = raw[kk2];
      af[kk2] = cv.s;
    }

    // ---- h-part MFMAs accumulate on top of the x-part ----
#pragma unroll
    for (int kk2 = 0; kk2 < 8; ++kk2)
#pragma unroll
      for (int ni = 0; ni < 4; ++ni)
        acc[ni] = __builtin_amdgcn_mfma_f32_16x16x32_bf16(af[kk2], wf[ni][kk2], acc[ni], 0, 0, 0);

    // ---- write partials to this parity's Gs ----
#pragma unroll
    for (int ni = 0; ni < 4; ++ni)
#pragma unroll
      for (int rr = 0; rr < 4; ++rr)
        Gs[t & 1][w][q * 4 + rr][ni * 16 + lr] = acc[ni][rr];
    __syncthreads();   // the ONLY barrier per step

    // ---- nonlinearity + per-wave-drained h store + counter-gated flag ----
    {
      const int upd = (t < len_b);
      const float (*G)[MROW][68] = Gs[t & 1];
      float s[4];
#pragma unroll
      for (int p = 0; p < 4; ++p) {
        const int cb = p * 16 + j1;
        s[p] = (G[0][bloc][cb] + G[1][bloc][cb]) + (G[2][bloc][cb] + G[3][bloc][cb]);
      }
      const float ig = sigmoidf_(s[0] + bias[0]);
      const float fg = sigmoidf_(s[1] + bias[1]);
      const float gg = tanhf_(s[2] + bias[2]);
      const float og = sigmoidf_(s[3] + bias[3]);
      const float cn = fg * creg + ig * gg;
      const float hn = og * tanhf_(cn);
      if (upd) { creg = cn; hreg = hn; }

      unsigned int hb16 = (unsigned int)f_to_bf16bits(hreg);
      unsigned int a01 = (hb16 & 0xFFFFu) | (__shfl_xor(hb16, 1) << 16);
      unsigned int a23 = __shfl_xor(a01, 2);
      unsigned int a45 = __shfl_xor(a01, 4);
      unsigned int a67 = __shfl_xor(a23, 4);
      if ((tid & 7) == 0) {
        i32x4 v; v[0] = (int)a01; v[1] = (int)a23; v[2] = (int)a45; v[3] = (int)a67;
        store16_sys(hstore_base + (size_t)((t + 1) & 1) * (B_ * H_ * 2) + poff, v);
      }
      asm volatile("s_waitcnt vmcnt(0)" ::: "memory");  // this wave's stores at LLC
      __builtin_amdgcn_sched_barrier(0);
      if (lane == 0) {
        int r = atomicAdd(&cnt[t & 1], 1);             // ds_add_rtn (LDS)
        if (r == 3) {                                   // 4th wave: all drained
          cnt[t & 1] = 0;                               // reset for step t+2
          __hip_atomic_store(&flags[bg * CG_ + cg], t + 1,
                             __ATOMIC_RELAXED, __HIP_MEMORY_SCOPE_AGENT);
        }
      }
    }

    // ---- prefetch flag sample for step t+1 (fire-and-forget) ----
    issue4_sys(myflag, fsamp);
  }

  asm volatile("s_waitcnt vmcnt(0)" ::: "memory");  // drain leftover sample
  out[b * H_ + jglob] = hreg;
  out[B_ * H_ + b * H_ + jglob] = creg;
}

// init: h0 -> hbuf[0] (bf16), zero flags. Re-runs every launch (graph replay safe).
__global__ void init_k(const float* __restrict__ h0, __hip_bfloat16* __restrict__ hbuf,
                       int* __restrict__ flags) {
  int i = blockIdx.x * 256 + threadIdx.x;
  if (i < B_ * H_) hbuf[i] = __float2bfloat16(h0[i]);
  if (i < NBLK) flags[i] = 0;
}

extern "C" void kernel_launch(void* const* d_in, const int* in_sizes, int n_in,
                              void* d_out, int out_size, void* d_ws, size_t ws_size,
                              hipStream_t stream) {
  const float* x       = (const float*)d_in[0];
  const int*   lengths = (const int*)d_in[1];
  const float* h0      = (const float*)d_in[2];
  const float* c0      = (const float*)d_in[3];
  const float* Wih     = (const float*)d_in[4];
  const float* Whh     = (const float*)d_in[5];
  const float* bih     = (const float*)d_in[6];
  const float* bhh     = (const float*)d_in[7];
  float* out = (float*)d_out;

  char* ws = (char*)d_ws;
  int* flags               = (int*)ws;                               // 8 KB region
  __hip_bfloat16* hbuf     = (__hip_bfloat16*)(ws + 8192);           // 2 x 64 KB

  hipLaunchKernelGGL(init_k, dim3(128), dim3(256), 0, stream, h0, hbuf, flags);
  hipLaunchKernelGGL(lstm_rec, dim3(NBLK), dim3(256), 0, stream,
                     x, Wih, Whh, lengths, h0, c0, bih, bhh, hbuf, flags, out);
}

// Round 18
// 7942.690 us; speedup vs baseline: 1.5209x; 1.5209x over previous
//
#include <hip/hip_runtime.h>
#include <hip/hip_bf16.h>

#define B_ 32
#define T_ 2048
#define D_ 512
#define H_ 1024
#define NBLK 128   // 2 batch-groups x 64 col-groups; 1 block/CU, co-resident
#define CG_ 64     // col groups
#define JPB 16     // h-columns per col-group (H_/CG_)
#define MROW 16    // batch rows per batch-group

typedef __attribute__((ext_vector_type(8))) short short8;
typedef __attribute__((ext_vector_type(4))) float f32x4;
typedef __attribute__((ext_vector_type(4))) int i32x4;

__device__ __forceinline__ float sigmoidf_(float x) { return 1.0f / (1.0f + __expf(-x)); }
__device__ __forceinline__ float tanhf_(float x) {
  float e = __expf(2.0f * x);
  return 1.0f - 2.0f / (e + 1.0f);
}
__device__ __forceinline__ unsigned short f_to_bf16bits(float f) {
  __hip_bfloat16 h = __float2bfloat16(f);
  return __builtin_bit_cast(unsigned short, h);
}

// 16B load bypassing L1/L2 (sc0 sc1): fresh from memory-side LLC, coalesces.
__device__ __forceinline__ i32x4 load16_sys(const void* p) {
  i32x4 v;
  asm volatile("global_load_dwordx4 %0, %1, off sc0 sc1" : "=v"(v) : "v"(p));
  return v;
}
// 4B LLC-fresh load, value ready on return (vmcnt inside). Coalesces.
__device__ __forceinline__ int load4_sys(const int* p) {
  int v;
  asm volatile("global_load_dword %0, %1, off sc0 sc1\n\t"
               "s_waitcnt vmcnt(0)"
               : "=v"(v) : "v"(p) : "memory");
  return v;
}
// 16B store written through to LLC (sc0 sc1); drained by explicit vmcnt(0).
__device__ __forceinline__ void store16_sys(void* p, i32x4 v) {
  asm volatile("global_store_dwordx4 %0, %1, off sc0 sc1" :: "v"(p), "v"(v) : "memory");
}

// ---------------------------------------------------------------------------
// FUSED persistent LSTM (R15, verified pre+post timing; best = 7.96 ms):
// 128 blocks x 256 thr (4 waves), batch-split. Block (bg,cg): gates for
// batches [bg*16,+16) x h-cols [cg*16,+16). Wave w: h-part K in [w*256,+256),
// x-part K in [w*128,+128). Per step: x-part (independent of h) fills the
// flag-wait bubble; coalesced 16-flag poll; sc0/sc1 h loads; 32 h-MFMAs
// accumulate onto the x-part; Gs (parity double-buffered) -> single barrier
// -> nonlinearity -> packed h store -> per-wave vmcnt(0) drain -> LDS counter;
// 4th-arriving wave resets the counter and posts the block flag.
// Safety induction (verified R12/R14/R15):
//  * flag=t+1 posted only after all 4 waves' h_{t+1} stores drained.
//  * h stores happen post-barrier => after ALL 4 waves' polls(t) saw their 16
//    producers >= t; union of the 4 poll sets = all 64 same-bg blocks = the
//    consumers of this block's h => every step t-1 read of hbuf[(t+1)&1]
//    completed before the overwrite.
//  * Gs parity + cnt parity ordered by the barrier chain (R13-verified).
// Deadlock-free: flags monotone; every wave always reaches its ds_add.
// ---------------------------------------------------------------------------
__global__ __launch_bounds__(256, 1) void lstm_rec(
    const float* __restrict__ x, const float* __restrict__ Wih,
    const float* __restrict__ Whh,
    const int* __restrict__ lengths, const float* __restrict__ h0,
    const float* __restrict__ c0, const float* __restrict__ bih,
    const float* __restrict__ bhh, __hip_bfloat16* hbuf,
    int* flags, float* __restrict__ out) {
  __shared__ float Gs[2][4][MROW][68];   // [parity][k-slice][batch row][gate col]
  __shared__ int cnt[2];                 // per-parity completion counters

  const int bid = blockIdx.x, tid = threadIdx.x;
  const int bg = bid & 1, cg = bid >> 1;
  const int lane = tid & 63, w = tid >> 6;
  const int lr = lane & 15, q = lane >> 4, kq = q * 8;
  const int kkb = w * 8;                 // h-part kk range [kkb,kkb+8)

  // --- W_hh fragments (stationary) ---
  short8 wf[4][8];
#pragma unroll
  for (int ni = 0; ni < 4; ++ni) {
    const int gcol = ni * H_ + cg * JPB + lr;
    const float* wbase = Whh + (size_t)gcol * H_ + kq;
#pragma unroll
    for (int kk2 = 0; kk2 < 8; ++kk2) {
      const int k0 = (kkb + kk2) * 32;
      f32x4 w0 = *(const f32x4*)(wbase + k0);
      f32x4 w1 = *(const f32x4*)(wbase + k0 + 4);
      __hip_bfloat16 tw_[8];
#pragma unroll
      for (int e = 0; e < 4; ++e) { tw_[e] = __float2bfloat16(w0[e]); tw_[4 + e] = __float2bfloat16(w1[e]); }
      wf[ni][kk2] = *(const short8*)&tw_[0];
    }
  }
  // --- W_ih fragments (stationary): x-part K-slice [w*128,+128) of D ---
  short8 wfx[4][4];
#pragma unroll
  for (int ni = 0; ni < 4; ++ni) {
    const int gcol = ni * H_ + cg * JPB + lr;
    const float* wbase = Wih + (size_t)gcol * D_ + w * 128 + kq;
#pragma unroll
    for (int kkx = 0; kkx < 4; ++kkx) {
      f32x4 w0 = *(const f32x4*)(wbase + kkx * 32);
      f32x4 w1 = *(const f32x4*)(wbase + kkx * 32 + 4);
      __hip_bfloat16 tw_[8];
#pragma unroll
      for (int e = 0; e < 4; ++e) { tw_[e] = __float2bfloat16(w0[e]); tw_[4 + e] = __float2bfloat16(w1[e]); }
      wfx[ni][kkx] = *(const short8*)&tw_[0];
    }
  }

  if (tid < 2) cnt[tid] = 0;   // visible to all by the step-0 barrier

  const int bloc = tid >> 4, j1 = tid & 15;
  const int b = bg * MROW + bloc;
  const int jglob = cg * JPB + j1;
  const int len_b = lengths[b];
  int maxlen = 0;
  for (int p = 0; p < B_; ++p) maxlen = max(maxlen, lengths[p]);
  const int tend = maxlen;

  float hreg = h0[b * H_ + jglob], creg = c0[b * H_ + jglob];
  float bias[4];
#pragma unroll
  for (int p = 0; p < 4; ++p) bias[p] = bih[p * H_ + jglob] + bhh[p * H_ + jglob];

  const int* myflag = &flags[bg * CG_ + w * 16 + lr];
  char* const hstore_base = (char*)hbuf;
  const size_t poff = (size_t)b * (H_ * 2) + cg * (JPB * 2) + ((tid >> 3) & 1) * 16;
  const float* xrow = x + (size_t)(bg * MROW + lr) * T_ * D_ + w * 128 + kq;

  for (int t = 0; t < tend; ++t) {
    // ---- x-part: load x (cacheable, L2/L3), convert, 16 MFMAs ----
    // Independent of h -> fills the flag-wait bubble.
    f32x4 acc[4];
#pragma unroll
    for (int ni = 0; ni < 4; ++ni) acc[ni] = (f32x4){0.f, 0.f, 0.f, 0.f};
    {
      const float* xt = xrow + (size_t)t * D_;
      short8 afx[4];
#pragma unroll
      for (int kkx = 0; kkx < 4; ++kkx) {
        f32x4 a0 = *(const f32x4*)(xt + kkx * 32);
        f32x4 a1 = *(const f32x4*)(xt + kkx * 32 + 4);
        __hip_bfloat16 ta_[8];
#pragma unroll
        for (int e = 0; e < 4; ++e) { ta_[e] = __float2bfloat16(a0[e]); ta_[4 + e] = __float2bfloat16(a1[e]); }
        afx[kkx] = *(const short8*)&ta_[0];
      }
#pragma unroll
      for (int kkx = 0; kkx < 4; ++kkx)
#pragma unroll
        for (int ni = 0; ni < 4; ++ni)
          acc[ni] = __builtin_amdgcn_mfma_f32_16x16x32_bf16(afx[kkx], wfx[ni][kkx], acc[ni], 0, 0, 0);
    }

    // ---- per-wave poll: ONE coalesced line read of 16 producer flags ----
    while (true) {
      int f = load4_sys(myflag);
      if (__all((lane >= 16) || (f >= t))) break;
      __builtin_amdgcn_s_sleep(1);
    }

    // ---- A-fragments: coalescing 16B L2-bypass loads (16 rows only) ----
    const char* hb = (const char*)(hbuf + (size_t)(t & 1) * (B_ * H_));
    const char* rowp = hb + (size_t)(bg * MROW + lr) * (H_ * 2) + kkb * 64 + q * 16;
    i32x4 raw[8];
#pragma unroll
    for (int kk2 = 0; kk2 < 8; ++kk2)
      raw[kk2] = load16_sys(rowp + kk2 * 64);
    asm volatile("s_waitcnt vmcnt(0)" ::: "memory");
    __builtin_amdgcn_sched_barrier(0);

    short8 af[8];
#pragma unroll
    for (int kk2 = 0; kk2 < 8; ++kk2) {
      union { i32x4 i; short8 s; } cv;
      cv.i = raw[kk2];
      af[kk2] = cv.s;
    }

    // ---- h-part MFMAs accumulate on top of the x-part ----
#pragma unroll
    for (int kk2 = 0; kk2 < 8; ++kk2)
#pragma unroll
      for (int ni = 0; ni < 4; ++ni)
        acc[ni] = __builtin_amdgcn_mfma_f32_16x16x32_bf16(af[kk2], wf[ni][kk2], acc[ni], 0, 0, 0);

    // ---- write partials to this parity's Gs ----
#pragma unroll
    for (int ni = 0; ni < 4; ++ni)
#pragma unroll
      for (int rr = 0; rr < 4; ++rr)
        Gs[t & 1][w][q * 4 + rr][ni * 16 + lr] = acc[ni][rr];
    __syncthreads();   // the ONLY barrier per step

    // ---- nonlinearity + per-wave-drained h store + counter-gated flag ----
    {
      const int upd = (t < len_b);
      const float (*G)[MROW][68] = Gs[t & 1];
      float s[4];
#pragma unroll
      for (int p = 0; p < 4; ++p) {
        const int cb = p * 16 + j1;
        s[p] = (G[0][bloc][cb] + G[1][bloc][cb]) + (G[2][bloc][cb] + G[3][bloc][cb]);
      }
      const float ig = sigmoidf_(s[0] + bias[0]);
      const float fg = sigmoidf_(s[1] + bias[1]);
      const float gg = tanhf_(s[2] + bias[2]);
      const float og = sigmoidf_(s[3] + bias[3]);
      const float cn = fg * creg + ig * gg;
      const float hn = og * tanhf_(cn);
      if (upd) { creg = cn; hreg = hn; }

      unsigned int hb16 = (unsigned int)f_to_bf16bits(hreg);
      unsigned int a01 = (hb16 & 0xFFFFu) | (__shfl_xor(hb16, 1) << 16);
      unsigned int a23 = __shfl_xor(a01, 2);
      unsigned int a45 = __shfl_xor(a01, 4);
      unsigned int a67 = __shfl_xor(a23, 4);
      if ((tid & 7) == 0) {
        i32x4 v; v[0] = (int)a01; v[1] = (int)a23; v[2] = (int)a45; v[3] = (int)a67;
        store16_sys(hstore_base + (size_t)((t + 1) & 1) * (B_ * H_ * 2) + poff, v);
      }
      asm volatile("s_waitcnt vmcnt(0)" ::: "memory");  // this wave's stores at LLC
      __builtin_amdgcn_sched_barrier(0);
      if (lane == 0) {
        int r = atomicAdd(&cnt[t & 1], 1);             // ds_add_rtn (LDS)
        if (r == 3) {                                   // 4th wave: all drained
          cnt[t & 1] = 0;                               // reset for step t+2
          __hip_atomic_store(&flags[bg * CG_ + cg], t + 1,
                             __ATOMIC_RELAXED, __HIP_MEMORY_SCOPE_AGENT);
        }
      }
    }
  }

  out[b * H_ + jglob] = hreg;
  out[B_ * H_ + b * H_ + jglob] = creg;
}

// init: h0 -> hbuf[0] (bf16), zero flags. Re-runs every launch (graph replay safe).
__global__ void init_k(const float* __restrict__ h0, __hip_bfloat16* __restrict__ hbuf,
                       int* __restrict__ flags) {
  int i = blockIdx.x * 256 + threadIdx.x;
  if (i < B_ * H_) hbuf[i] = __float2bfloat16(h0[i]);
  if (i < NBLK) flags[i] = 0;
}

extern "C" void kernel_launch(void* const* d_in, const int* in_sizes, int n_in,
                              void* d_out, int out_size, void* d_ws, size_t ws_size,
                              hipStream_t stream) {
  const float* x       = (const float*)d_in[0];
  const int*   lengths = (const int*)d_in[1];
  const float* h0      = (const float*)d_in[2];
  const float* c0      = (const float*)d_in[3];
  const float* Wih     = (const float*)d_in[4];
  const float* Whh     = (const float*)d_in[5];
  const float* bih     = (const float*)d_in[6];
  const float* bhh     = (const float*)d_in[7];
  float* out = (float*)d_out;

  char* ws = (char*)d_ws;
  int* flags               = (int*)ws;                               // 8 KB region
  __hip_bfloat16* hbuf     = (__hip_bfloat16*)(ws + 8192);           // 2 x 64 KB

  hipLaunchKernelGGL(init_k, dim3(128), dim3(256), 0, stream, h0, hbuf, flags);
  hipLaunchKernelGGL(lstm_rec, dim3(NBLK), dim3(256), 0, stream,
                     x, Wih, Whh, lengths, h0, c0, bih, bhh, hbuf, flags, out);
}